// Round 14
// baseline (103.878 us; speedup 1.0000x reference)
//
#include <hip/hip_runtime.h>
#include <hip/hip_bf16.h>

#define BSZ 32
#define CIN 128
#define CD 64
#define HH 64
#define WW 64
#define PLANE (HH * WW)
#define NPIX (BSZ * HH * WW)
#define NB 8
#define BN_EPS 1e-5f

typedef __attribute__((ext_vector_type(8))) short short8v;
typedef __attribute__((ext_vector_type(4))) float f32x4;
typedef __attribute__((ext_vector_type(4))) unsigned int u32x4;

static __device__ __forceinline__ short f2bf(float f) {
    __hip_bfloat16 h = __float2bfloat16(f);
    return __builtin_bit_cast(short, h);
}
static __device__ __forceinline__ float bf2f(unsigned short u) {
    return __builtin_bit_cast(float, (unsigned)u << 16);
}
// packed bf16 convert: dst.lo16 = bf16(lo), dst.hi16 = bf16(hi) (RNE)
static __device__ __forceinline__ unsigned int cvtpk(float lo, float hi) {
    unsigned int r;
    asm("v_cvt_pk_bf16_f32 %0, %1, %2" : "=v"(r) : "v"(lo), "v"(hi));
    return r;
}
// closed-form uniform cubic B-spline 8-slot window, funnel-shift placement
// (verified rounds 6-13; round-13 funnel form).
static __device__ __forceinline__ u32x4 basisD(float v) {
    const float tt = (v + 2.2f) * 2.5f;
    const float fi = floorf(tt);
    const int i0 = (int)fi;
    const float u = tt - fi;
    const bool inr = (tt >= 0.0f) && (tt < 11.0f);
    const float u2 = u * u, u3 = u2 * u;
    const float t1 = 1.f - u;
    const float w0 = (1.f / 6.f) * t1 * t1 * t1;
    const float w3 = (1.f / 6.f) * u3;
    const float w1 = fmaf(0.5f, u3, 2.f / 3.f) - u2;
    const float w2 = 1.f - w0 - w1 - w3;
    unsigned W01 = cvtpk(w0, w1);
    unsigned W23 = cvtpk(w2, w3);
    if (!inr) { W01 = 0u; W23 = 0u; }
    const unsigned long long P =
        ((unsigned long long)W23 << 32) | (unsigned long long)W01;
    const int t = (i0 - 3) << 4;
    const unsigned long long S1 = P << (t & 63);
    const unsigned long long S2 = P >> ((64 - t) & 63);
    const bool c1 = (unsigned)t < 64u;
    const bool c2 = t < 0;
    const bool c3 = t >= 64;
    const bool c5 = t > 0;
    const unsigned long long lo = c1 ? S1 : (c2 ? S2 : 0ULL);
    const unsigned long long hi = c3 ? S1 : ((c1 && c5) ? S2 : 0ULL);
    u32x4 D;
    D.x = (unsigned)lo;
    D.y = (unsigned)(lo >> 32);
    D.z = (unsigned)hi;
    D.w = (unsigned)(hi >> 32);
    return D;
}
// rebuild tile0/tile1 bf16 A-frags from a [ch][17] (tile0,tile1)-pair pad
static __device__ __forceinline__ void gather_frags(
    const unsigned* __restrict__ pad, int s3, int hi, int m,
    short8v& f0, short8v& f1)
{
    unsigned q[8];
#pragma unroll
    for (int e = 0; e < 8; ++e) q[e] = pad[(s3 * 32 + 8 * hi + e) * 17 + m];
#pragma unroll
    for (int qi = 0; qi < 4; ++qi) {
        ((unsigned*)&f0)[qi] = (q[2 * qi] & 0xffffu) | (q[2 * qi + 1] << 16);
        ((unsigned*)&f1)[qi] = (q[2 * qi] >> 16) | (q[2 * qi + 1] & 0xffff0000u);
    }
}

// ---------------------------------------------------------------------------
// K0: prepack weights into MFMA B-fragment order (bf16) + fold BN.
// Fragment layout (verified round 2): element ((s*4+c)*64+l)*8+e holds
// W[k = s*32 + (l>>4)*8 + e][j = c*16 + (l&15)].
// ---------------------------------------------------------------------------
__global__ __launch_bounds__(256) void k_prep(
    const float* __restrict__ coef, const float* __restrict__ ssp,
    const float* __restrict__ sb, const float* __restrict__ f2w,
    const float* __restrict__ reduce_w, const float* __restrict__ g_w,
    const float* __restrict__ dw_g, const float* __restrict__ dw_beta,
    const float* __restrict__ dw_m, const float* __restrict__ dw_v,
    const float* __restrict__ dw_b, const float* __restrict__ g_g,
    const float* __restrict__ g_beta, const float* __restrict__ g_m,
    const float* __restrict__ g_v, const float* __restrict__ g_b,
    short* __restrict__ W1f, short* __restrict__ W2f,
    short* __restrict__ WRf, short* __restrict__ WGf,
    float* __restrict__ cbuf)
{
    const int idx = blockIdx.x * 256 + threadIdx.x;
    if (idx < 36864) {
        const int e = idx & 7, l = (idx >> 3) & 63, c = (idx >> 9) & 3, s = idx >> 11;
        const int k = s * 32 + ((l >> 4) << 3) + e;
        const int j = (c << 4) + (l & 15);
        float v;
        if (k < 512) {
            const int i = k >> 3, t = k & 7;
            v = coef[(i * 64 + j) * 8 + t] * ssp[i * 64 + j];
        } else {
            v = sb[(k - 512) * 64 + j];
        }
        W1f[idx] = f2bf(v);
    } else if (idx < 45056) {
        const int f = idx - 36864;
        const int e = f & 7, l = (f >> 3) & 63, c = (f >> 9) & 3, s = f >> 11;
        const int k = s * 32 + ((l >> 4) << 3) + e;
        const int j = (c << 4) + (l & 15);
        W2f[f] = f2bf(f2w[j * 64 + k]);
    } else if (idx < 53248) {
        const int f = idx - 45056;
        const int e = f & 7, l = (f >> 3) & 63, c = (f >> 9) & 3, s = f >> 11;
        const int k = s * 32 + ((l >> 4) << 3) + e;
        const int j = (c << 4) + (l & 15);
        WRf[f] = f2bf(reduce_w[j * CIN + k]);
    } else if (idx < 57344) {
        const int f = idx - 53248;
        const int e = f & 7, l = (f >> 3) & 63, c = (f >> 9) & 3, s = f >> 11;
        const int k = s * 32 + ((l >> 4) << 3) + e;
        const int j = (c << 4) + (l & 15);
        WGf[f] = f2bf(g_w[j * 64 + k]);
    } else if (idx < 57600) {
        const int q = (idx - 57344) >> 6, c = idx & 63;
        if (q == 0) cbuf[c] = dw_g[c] * rsqrtf(dw_v[c] + BN_EPS);
        else if (q == 1) {
            float sc = dw_g[c] * rsqrtf(dw_v[c] + BN_EPS);
            cbuf[64 + c] = (dw_b[c] - dw_m[c]) * sc + dw_beta[c];
        } else if (q == 2) cbuf[128 + c] = g_g[c] * rsqrtf(g_v[c] + BN_EPS);
        else {
            float sc = g_g[c] * rsqrtf(g_v[c] + BN_EPS);
            cbuf[192 + c] = (g_b[c] - g_m[c]) * sc + g_beta[c];
        }
    }
}

// ---------------------------------------------------------------------------
// K1: 1x1 conv 128->64 via MFMA. ROUND 14: output bf16 (paired cvtpk
// epilogue, uint stores) — halves WRITE traffic. Structure unchanged.
// ---------------------------------------------------------------------------
__global__ __launch_bounds__(256) void k_reduce_mfma(
    const float* __restrict__ x, const short* __restrict__ WRf,
    const float* __restrict__ bias, unsigned short* __restrict__ out)
{
    __shared__ __align__(16) char smem[34048];
    short* As = (short*)smem;
    float* Osh = (float*)smem;
    const int bid = blockIdx.x;
    const int b = bid >> 5, h0 = (bid & 31) * 2;
    const int tid = threadIdx.x;
    const float* xb = x + (size_t)b * CIN * PLANE + h0 * WW;
#pragma unroll 1
    for (int p = 0; p < 64; ++p) {
        const int idx = tid + (p << 8);
        const int c = idx >> 7, rt = idx & 127;
        const float v = xb[(size_t)c * PLANE + rt];
        const int s = c >> 5, g = (c >> 3) & 3, e = c & 7;
        const int mt = rt >> 4, m = rt & 15;
        As[((mt * 4 + s) * 64 + (((g << 4) | m) ^ (s & 7))) * 8 + e] = f2bf(v);
    }
    __syncthreads();
    const int cw = tid >> 6, l = tid & 63;
    f32x4 acc[8];
#pragma unroll
    for (int i = 0; i < 8; ++i) acc[i] = (f32x4){0.f, 0.f, 0.f, 0.f};
#pragma unroll 1
    for (int s = 0; s < 4; ++s) {
        const short8v bfr = *(const short8v*)&WRf[((s * 4 + cw) * 64 + l) * 8];
        const int lx = l ^ (s & 7);
#pragma unroll
        for (int mt = 0; mt < 8; ++mt) {
            const short8v a = *(const short8v*)&As[((mt * 4 + s) * 64 + lx) * 8];
            acc[mt] = __builtin_amdgcn_mfma_f32_16x16x32_bf16(a, bfr, acc[mt], 0, 0, 0);
        }
    }
    __syncthreads();
    const int j = (cw << 4) + (l & 15);
    const float bj = bias[j];
    const int rb = (l >> 4) << 2;
#pragma unroll
    for (int mt = 0; mt < 8; ++mt)
#pragma unroll
        for (int r = 0; r < 4; ++r)
            Osh[j * 133 + mt * 16 + rb + r] = acc[mt][r] + bj;
    __syncthreads();
    unsigned short* ob = out + (size_t)b * CD * PLANE + h0 * WW;
#pragma unroll 1
    for (int p = 0; p < 16; ++p) {
        const int idx = tid + (p << 8);
        const int jj = idx >> 6, rt2 = (idx & 63) * 2;
        const unsigned pk = cvtpk(Osh[jj * 133 + rt2], Osh[jj * 133 + rt2 + 1]);
        *(unsigned*)&ob[(size_t)jj * PLANE + rt2] = pk;
    }
}

// ---------------------------------------------------------------------------
// K2/K5: 7x7 depthwise conv, register-streaming, quarter-plane strips.
// ROUND 14: bf16 in/out (RESID=false) and bf16 in/resid + fp32 out
// (RESID=true). Structure unchanged from round 6.
// ---------------------------------------------------------------------------
template<bool RESID>
__global__ __launch_bounds__(256) void k_dwconv(
    const unsigned short* __restrict__ in, const float* __restrict__ filt,
    const float* __restrict__ sc, const float* __restrict__ shv,
    const unsigned short* __restrict__ resid, void* __restrict__ outv)
{
    const int bid = blockIdx.x;
    const int b = bid >> 6, c4 = (bid >> 2) & 15, strip = bid & 3;
    const int H0 = strip << 4;
    const int c = c4 * 4 + (threadIdx.x >> 6);
    const int lane = threadIdx.x & 63;
    const size_t pbase = ((size_t)b * CD + c) * PLANE;
    const unsigned short* plane = in + pbase;
    const float* wp = filt + c * 49;
    float K[49];
#pragma unroll
    for (int q = 0; q < 49; ++q) K[q] = wp[q];
    const float scl = RESID ? 1.f : sc[c];
    const float shf = shv[c];
    const unsigned short* rplane = RESID ? (resid + pbase) : nullptr;
    float* oplane_f = RESID ? ((float*)outv + pbase) : nullptr;
    unsigned short* oplane_h = RESID ? nullptr : ((unsigned short*)outv + pbase);

    float acc[7] = {0.f, 0.f, 0.f, 0.f, 0.f, 0.f, 0.f};
#pragma unroll
    for (int rr = 0; rr < 22; ++rr) {
        const int ra = H0 + rr - 3;
        float rowv = 0.f;
        if (ra >= 0 && ra < 64) rowv = bf2f(plane[ra * 64 + lane]);
        float sh[7];
        sh[3] = rowv;
#pragma unroll
        for (int d = 1; d <= 3; ++d) {
            float tp = __shfl(rowv, lane + d);
            sh[3 + d] = (lane + d < 64) ? tp : 0.f;
            float tm = __shfl(rowv, lane - d);
            sh[3 - d] = (lane - d >= 0) ? tm : 0.f;
        }
#pragma unroll
        for (int dy = 0; dy < 7; ++dy) {
            const int o = rr - dy;
            if (o >= 0 && o < 16) {
                const int slot = o % 7;
#pragma unroll
                for (int dx = 0; dx < 7; ++dx)
                    acc[slot] = fmaf(sh[dx], K[dy * 7 + dx], acc[slot]);
            }
        }
        const int done = rr - 6;
        if (done >= 0 && done < 16) {
            const int slot = done % 7;
            const int h = H0 + done;
            if (RESID) {
                oplane_f[h * 64 + lane] =
                    acc[slot] + shf + bf2f(rplane[h * 64 + lane]);
            } else {
                oplane_h[h * 64 + lane] =
                    (unsigned short)(unsigned short)f2bf(acc[slot] * scl + shf);
            }
            acc[slot] = 0.f;
        }
    }
}

// ---------------------------------------------------------------------------
// K3: fused KAN + f2 + gate + g-conv + BN via bf16 MFMA.
// ROUND 14: xd input bf16 (scalar ushort loads + <<16 convert; basis/silu on
// the bf16-rounded v — same value the GEMM path already used), z output
// bf16 (uint2 packed stores). Structure identical to round 13.
// ---------------------------------------------------------------------------
__global__ __launch_bounds__(256) void k_kan_fused(
    const unsigned short* __restrict__ xd, const short* __restrict__ W1f,
    const short* __restrict__ W2f, const short* __restrict__ WGf,
    const float* __restrict__ kb, const float* __restrict__ f2b,
    const float* __restrict__ gs, const float* __restrict__ gsh,
    unsigned short* __restrict__ z)
{
    __shared__ __align__(16) short As1[2 * 18 * 64 * 8];  // 36 KB
    __shared__ __align__(16) short As2[2 * 2 * 64 * 8];   //  4 KB
    __shared__ unsigned yPad[64 * 17];                    // 4.25 KB
    const int tid = threadIdx.x;
    const int tg0 = blockIdx.x * 32;
    const int bb = tg0 >> 12, pix0 = tg0 & 4095;
    const unsigned short* xb = xd + (size_t)bb * CD * PLANE + pix0;
    unsigned short* zb = z + (size_t)bb * CD * PLANE + pix0;
    const int tkn = tid & 31;
    const int w5 = tid >> 5;
    const int mt = tkn >> 4, m = tkn & 15;

    // ---- staging: basis + silu + v fragments (round-6 verified layout) ----
    float vf[8], sf[8];
#pragma unroll
    for (int p = 0; p < 8; ++p) {
        const int c = w5 * 8 + p;
        const float v = bf2f(xb[(size_t)c * PLANE + tkn]);
        vf[p] = v;
        sf[p] = v * __builtin_amdgcn_rcpf(1.0f + __expf(-v));
        const u32x4 D = basisD(v);
        const int s = w5 * 2 + (p >> 2);
        const int phys = (((p & 3) << 4) | m) ^ (s & 7);
        *(u32x4*)&As1[((mt * 18 + s) * 64 + phys) * 8] = D;
    }
    {   // silu + raw-v fragments: one b128 store each
        short8v vpk, spk;
#pragma unroll
        for (int q = 0; q < 4; ++q) {
            ((unsigned*)&vpk)[q] = cvtpk(vf[2 * q], vf[2 * q + 1]);
            ((unsigned*)&spk)[q] = cvtpk(sf[2 * q], sf[2 * q + 1]);
        }
        const int slot = ((w5 & 3) << 4) | m;
        const int s2 = 16 + (w5 >> 2);
        *(short8v*)&As1[((mt * 18 + s2) * 64 + (slot ^ (s2 & 7))) * 8] = spk;
        const int s3 = w5 >> 2;
        *(short8v*)&As2[((mt * 2 + s3) * 64 + (slot ^ (s3 & 7))) * 8] = vpk;
    }
    __syncthreads();   // B1: staging complete

    const int cw = tid >> 6, l = tid & 63;
    const int hi = l >> 4;
    const int j = (cw << 4) + (l & 15);
    const int mq = l & 15;
    const int rb = hi << 2;
    const float kbj = kb[j], f2bj = f2b[j];
    const float sj = gs[j], hj = gsh[j];

    // ---- GEMM1 (K=576, fully unrolled) + GEMM2 ----
    f32x4 accA0 = {0.f,0.f,0.f,0.f}, accA1 = {0.f,0.f,0.f,0.f};
    f32x4 accB0 = {0.f,0.f,0.f,0.f}, accB1 = {0.f,0.f,0.f,0.f};
#pragma unroll
    for (int s = 0; s < 18; ++s) {
        const short8v bfr = *(const short8v*)&W1f[((s * 4 + cw) * 64 + l) * 8];
        const short8v a0 = *(const short8v*)&As1[((0 * 18 + s) * 64 + (l ^ (s & 7))) * 8];
        const short8v a1 = *(const short8v*)&As1[((1 * 18 + s) * 64 + (l ^ (s & 7))) * 8];
        accA0 = __builtin_amdgcn_mfma_f32_16x16x32_bf16(a0, bfr, accA0, 0, 0, 0);
        accA1 = __builtin_amdgcn_mfma_f32_16x16x32_bf16(a1, bfr, accA1, 0, 0, 0);
    }
#pragma unroll
    for (int s = 0; s < 2; ++s) {
        const short8v bfr = *(const short8v*)&W2f[((s * 4 + cw) * 64 + l) * 8];
        const short8v a0 = *(const short8v*)&As2[((0 * 2 + s) * 64 + (l ^ s)) * 8];
        const short8v a1 = *(const short8v*)&As2[((1 * 2 + s) * 64 + (l ^ s)) * 8];
        accB0 = __builtin_amdgcn_mfma_f32_16x16x32_bf16(a0, bfr, accB0, 0, 0, 0);
        accB1 = __builtin_amdgcn_mfma_f32_16x16x32_bf16(a1, bfr, accB1, 0, 0, 0);
    }

    // ---- gate: y pairs into yPad ----
#pragma unroll
    for (int r = 0; r < 4; ++r) {
        const float ya = (accA0[r] + kbj) * (accB0[r] + f2bj);
        const float yb = (accA1[r] + kbj) * (accB1[r] + f2bj);
        yPad[j * 17 + rb + r] = cvtpk(ya, yb);
    }
    __syncthreads();   // B2

    // ---- GEMM3: z = y @ g_w^T ----
    f32x4 acc30 = {0.f,0.f,0.f,0.f}, acc31 = {0.f,0.f,0.f,0.f};
#pragma unroll
    for (int s3 = 0; s3 < 2; ++s3) {
        const short8v bfr = *(const short8v*)&WGf[((s3 * 4 + cw) * 64 + l) * 8];
        short8v f0, f1;
        gather_frags(yPad, s3, hi, mq, f0, f1);
        acc30 = __builtin_amdgcn_mfma_f32_16x16x32_bf16(f0, bfr, acc30, 0, 0, 0);
        acc31 = __builtin_amdgcn_mfma_f32_16x16x32_bf16(f1, bfr, acc31, 0, 0, 0);
    }

    // ---- epilogue: BN + bf16 packed NCHW stores ----
    uint2 p0, p1;
    p0.x = cvtpk(acc30[0] * sj + hj, acc30[1] * sj + hj);
    p0.y = cvtpk(acc30[2] * sj + hj, acc30[3] * sj + hj);
    p1.x = cvtpk(acc31[0] * sj + hj, acc31[1] * sj + hj);
    p1.y = cvtpk(acc31[2] * sj + hj, acc31[3] * sj + hj);
    *(uint2*)&zb[(size_t)j * PLANE + rb] = p0;
    *(uint2*)&zb[(size_t)j * PLANE + 16 + rb] = p1;
}

// ---------------------------------------------------------------------------
extern "C" void kernel_launch(void* const* d_in, const int* in_sizes, int n_in,
                              void* d_out, int out_size, void* d_ws, size_t ws_size,
                              hipStream_t stream)
{
    (void)in_sizes; (void)n_in; (void)out_size; (void)ws_size;
    const float* x        = (const float*)d_in[0];
    const float* reduce_w = (const float*)d_in[1];
    const float* reduce_b = (const float*)d_in[2];
    const float* dw_w     = (const float*)d_in[3];
    const float* dw_b     = (const float*)d_in[4];
    const float* dw_g     = (const float*)d_in[5];
    const float* dw_beta  = (const float*)d_in[6];
    const float* dw_m     = (const float*)d_in[7];
    const float* dw_v     = (const float*)d_in[8];
    const float* f2_w     = (const float*)d_in[9];
    const float* f2_b     = (const float*)d_in[10];
    const float* coef     = (const float*)d_in[11];
    const float* sbase    = (const float*)d_in[12];
    const float* ssp      = (const float*)d_in[13];
    const float* kbias    = (const float*)d_in[14];
    const float* g_w      = (const float*)d_in[15];
    const float* g_b      = (const float*)d_in[16];
    const float* g_g      = (const float*)d_in[17];
    const float* g_beta   = (const float*)d_in[18];
    const float* g_m      = (const float*)d_in[19];
    const float* g_v      = (const float*)d_in[20];
    const float* dw2_w    = (const float*)d_in[21];
    const float* dw2_b    = (const float*)d_in[22];
    float* out = (float*)d_out;

    const size_t NEL = (size_t)BSZ * CD * PLANE;
    short* W1f = (short*)d_ws;
    short* W2f = W1f + 36864;
    short* WRf = W2f + 8192;
    short* WGf = WRf + 8192;
    float* cbuf = (float*)((char*)d_ws + 115200);
    unsigned short* inp = (unsigned short*)((char*)d_ws + 131072);  // bf16
    unsigned short* xdb = inp + NEL;                                // bf16
    unsigned short* z   = xdb + NEL;                                // bf16

    k_prep<<<225, 256, 0, stream>>>(coef, ssp, sbase, f2_w, reduce_w, g_w,
                                    dw_g, dw_beta, dw_m, dw_v, dw_b,
                                    g_g, g_beta, g_m, g_v, g_b,
                                    W1f, W2f, WRf, WGf, cbuf);
    k_reduce_mfma<<<BSZ * 32, 256, 0, stream>>>(x, WRf, reduce_b, inp);
    k_dwconv<false><<<BSZ * 16 * 4, 256, 0, stream>>>(inp, dw_w, cbuf, cbuf + 64, nullptr, xdb);
    k_kan_fused<<<NPIX / 32, 256, 0, stream>>>(xdb, W1f, W2f, WGf, kbias, f2_b,
                                               cbuf + 128, cbuf + 192, z);
    k_dwconv<true><<<BSZ * 16 * 4, 256, 0, stream>>>(z, dw2_w, nullptr, dw2_b, inp, out);
}

// Round 15
// 97.151 us; speedup vs baseline: 1.0692x; 1.0692x over previous
//
#include <hip/hip_runtime.h>
#include <hip/hip_bf16.h>

#define BSZ 32
#define CIN 128
#define CD 64
#define HH 64
#define WW 64
#define PLANE (HH * WW)
#define NPIX (BSZ * HH * WW)
#define NB 8
#define BN_EPS 1e-5f

typedef __attribute__((ext_vector_type(8))) short short8v;
typedef __attribute__((ext_vector_type(4))) float f32x4;
typedef __attribute__((ext_vector_type(4))) unsigned int u32x4;

static __device__ __forceinline__ short f2bf(float f) {
    __hip_bfloat16 h = __float2bfloat16(f);
    return __builtin_bit_cast(short, h);
}
static __device__ __forceinline__ float bf2f(unsigned short u) {
    return __builtin_bit_cast(float, (unsigned)u << 16);
}
// packed bf16 convert: dst.lo16 = bf16(lo), dst.hi16 = bf16(hi) (RNE)
static __device__ __forceinline__ unsigned int cvtpk(float lo, float hi) {
    unsigned int r;
    asm("v_cvt_pk_bf16_f32 %0, %1, %2" : "=v"(r) : "v"(lo), "v"(hi));
    return r;
}
// closed-form uniform cubic B-spline 8-slot window, funnel-shift placement
// (verified rounds 6-14).
static __device__ __forceinline__ u32x4 basisD(float v) {
    const float tt = (v + 2.2f) * 2.5f;
    const float fi = floorf(tt);
    const int i0 = (int)fi;
    const float u = tt - fi;
    const bool inr = (tt >= 0.0f) && (tt < 11.0f);
    const float u2 = u * u, u3 = u2 * u;
    const float t1 = 1.f - u;
    const float w0 = (1.f / 6.f) * t1 * t1 * t1;
    const float w3 = (1.f / 6.f) * u3;
    const float w1 = fmaf(0.5f, u3, 2.f / 3.f) - u2;
    const float w2 = 1.f - w0 - w1 - w3;
    unsigned W01 = cvtpk(w0, w1);
    unsigned W23 = cvtpk(w2, w3);
    if (!inr) { W01 = 0u; W23 = 0u; }
    const unsigned long long P =
        ((unsigned long long)W23 << 32) | (unsigned long long)W01;
    const int t = (i0 - 3) << 4;
    const unsigned long long S1 = P << (t & 63);
    const unsigned long long S2 = P >> ((64 - t) & 63);
    const bool c1 = (unsigned)t < 64u;
    const bool c2 = t < 0;
    const bool c3 = t >= 64;
    const bool c5 = t > 0;
    const unsigned long long lo = c1 ? S1 : (c2 ? S2 : 0ULL);
    const unsigned long long hi = c3 ? S1 : ((c1 && c5) ? S2 : 0ULL);
    u32x4 D;
    D.x = (unsigned)lo;
    D.y = (unsigned)(lo >> 32);
    D.z = (unsigned)hi;
    D.w = (unsigned)(hi >> 32);
    return D;
}
// rebuild tile0/tile1 bf16 A-frags from a [ch][17] (tile0,tile1)-pair pad
static __device__ __forceinline__ void gather_frags(
    const unsigned* __restrict__ pad, int s3, int hi, int m,
    short8v& f0, short8v& f1)
{
    unsigned q[8];
#pragma unroll
    for (int e = 0; e < 8; ++e) q[e] = pad[(s3 * 32 + 8 * hi + e) * 17 + m];
#pragma unroll
    for (int qi = 0; qi < 4; ++qi) {
        ((unsigned*)&f0)[qi] = (q[2 * qi] & 0xffffu) | (q[2 * qi + 1] << 16);
        ((unsigned*)&f1)[qi] = (q[2 * qi] >> 16) | (q[2 * qi + 1] & 0xffff0000u);
    }
}

// ---------------------------------------------------------------------------
// K0: prepack weights into MFMA B-fragment order (bf16) + fold BN.
// Fragment layout (verified round 2): element ((s*4+c)*64+l)*8+e holds
// W[k = s*32 + (l>>4)*8 + e][j = c*16 + (l&15)].
// ---------------------------------------------------------------------------
__global__ __launch_bounds__(256) void k_prep(
    const float* __restrict__ coef, const float* __restrict__ ssp,
    const float* __restrict__ sb, const float* __restrict__ f2w,
    const float* __restrict__ reduce_w, const float* __restrict__ g_w,
    const float* __restrict__ dw_g, const float* __restrict__ dw_beta,
    const float* __restrict__ dw_m, const float* __restrict__ dw_v,
    const float* __restrict__ dw_b, const float* __restrict__ g_g,
    const float* __restrict__ g_beta, const float* __restrict__ g_m,
    const float* __restrict__ g_v, const float* __restrict__ g_b,
    short* __restrict__ W1f, short* __restrict__ W2f,
    short* __restrict__ WRf, short* __restrict__ WGf,
    float* __restrict__ cbuf)
{
    const int idx = blockIdx.x * 256 + threadIdx.x;
    if (idx < 36864) {
        const int e = idx & 7, l = (idx >> 3) & 63, c = (idx >> 9) & 3, s = idx >> 11;
        const int k = s * 32 + ((l >> 4) << 3) + e;
        const int j = (c << 4) + (l & 15);
        float v;
        if (k < 512) {
            const int i = k >> 3, t = k & 7;
            v = coef[(i * 64 + j) * 8 + t] * ssp[i * 64 + j];
        } else {
            v = sb[(k - 512) * 64 + j];
        }
        W1f[idx] = f2bf(v);
    } else if (idx < 45056) {
        const int f = idx - 36864;
        const int e = f & 7, l = (f >> 3) & 63, c = (f >> 9) & 3, s = f >> 11;
        const int k = s * 32 + ((l >> 4) << 3) + e;
        const int j = (c << 4) + (l & 15);
        W2f[f] = f2bf(f2w[j * 64 + k]);
    } else if (idx < 53248) {
        const int f = idx - 45056;
        const int e = f & 7, l = (f >> 3) & 63, c = (f >> 9) & 3, s = f >> 11;
        const int k = s * 32 + ((l >> 4) << 3) + e;
        const int j = (c << 4) + (l & 15);
        WRf[f] = f2bf(reduce_w[j * CIN + k]);
    } else if (idx < 57344) {
        const int f = idx - 53248;
        const int e = f & 7, l = (f >> 3) & 63, c = (f >> 9) & 3, s = f >> 11;
        const int k = s * 32 + ((l >> 4) << 3) + e;
        const int j = (c << 4) + (l & 15);
        WGf[f] = f2bf(g_w[j * 64 + k]);
    } else if (idx < 57600) {
        const int q = (idx - 57344) >> 6, c = idx & 63;
        if (q == 0) cbuf[c] = dw_g[c] * rsqrtf(dw_v[c] + BN_EPS);
        else if (q == 1) {
            float sc = dw_g[c] * rsqrtf(dw_v[c] + BN_EPS);
            cbuf[64 + c] = (dw_b[c] - dw_m[c]) * sc + dw_beta[c];
        } else if (q == 2) cbuf[128 + c] = g_g[c] * rsqrtf(g_v[c] + BN_EPS);
        else {
            float sc = g_g[c] * rsqrtf(g_v[c] + BN_EPS);
            cbuf[192 + c] = (g_b[c] - g_m[c]) * sc + g_beta[c];
        }
    }
}

// ---------------------------------------------------------------------------
// K1: 1x1 conv 128->64 via MFMA, bf16 out.
// ROUND 15: staging vectorized by channel-PAIRS — load (c, c+1) of one token
// (two coalesced streams), one cvtpk, one aligned u32 fragment store
// (e = c&7 even, same s/g for both). 32 passes instead of 64.
// ---------------------------------------------------------------------------
__global__ __launch_bounds__(256) void k_reduce_mfma(
    const float* __restrict__ x, const short* __restrict__ WRf,
    const float* __restrict__ bias, unsigned short* __restrict__ out)
{
    __shared__ __align__(16) char smem[34048];
    short* As = (short*)smem;
    float* Osh = (float*)smem;
    const int bid = blockIdx.x;
    const int b = bid >> 5, h0 = (bid & 31) * 2;
    const int tid = threadIdx.x;
    const float* xb = x + (size_t)b * CIN * PLANE + h0 * WW;
#pragma unroll 1
    for (int p = 0; p < 32; ++p) {
        const int idx = tid + (p << 8);          // 0..8191 channel-pair slots
        const int cpr = idx >> 7, rt = idx & 127;
        const int ca = cpr * 2;                  // even channel
        const float v0 = xb[(size_t)ca * PLANE + rt];
        const float v1 = xb[(size_t)(ca + 1) * PLANE + rt];
        const unsigned pk = cvtpk(v0, v1);
        const int s = ca >> 5, g = (ca >> 3) & 3, e = ca & 7;  // e even
        const int mt = rt >> 4, m = rt & 15;
        *(unsigned*)&As[((mt * 4 + s) * 64 + (((g << 4) | m) ^ (s & 7))) * 8 + e] = pk;
    }
    __syncthreads();
    const int cw = tid >> 6, l = tid & 63;
    f32x4 acc[8];
#pragma unroll
    for (int i = 0; i < 8; ++i) acc[i] = (f32x4){0.f, 0.f, 0.f, 0.f};
#pragma unroll 1
    for (int s = 0; s < 4; ++s) {
        const short8v bfr = *(const short8v*)&WRf[((s * 4 + cw) * 64 + l) * 8];
        const int lx = l ^ (s & 7);
#pragma unroll
        for (int mt = 0; mt < 8; ++mt) {
            const short8v a = *(const short8v*)&As[((mt * 4 + s) * 64 + lx) * 8];
            acc[mt] = __builtin_amdgcn_mfma_f32_16x16x32_bf16(a, bfr, acc[mt], 0, 0, 0);
        }
    }
    __syncthreads();
    const int j = (cw << 4) + (l & 15);
    const float bj = bias[j];
    const int rb = (l >> 4) << 2;
#pragma unroll
    for (int mt = 0; mt < 8; ++mt)
#pragma unroll
        for (int r = 0; r < 4; ++r)
            Osh[j * 133 + mt * 16 + rb + r] = acc[mt][r] + bj;
    __syncthreads();
    unsigned short* ob = out + (size_t)b * CD * PLANE + h0 * WW;
#pragma unroll 1
    for (int p = 0; p < 16; ++p) {
        const int idx = tid + (p << 8);
        const int jj = idx >> 6, rt2 = (idx & 63) * 2;
        const unsigned pk = cvtpk(Osh[jj * 133 + rt2], Osh[jj * 133 + rt2 + 1]);
        *(unsigned*)&ob[(size_t)jj * PLANE + rt2] = pk;
    }
}

// ---------------------------------------------------------------------------
// K2/K5: 7x7 depthwise conv, register-streaming, quarter-plane strips.
// ROUND 15: explicit two-phase — preload ALL 22 input rows into VGPRs
// (22 independent loads in flight; VGPR_Count 48 showed the compiler was
// NOT hoisting them, exposing per-row load latency serially), then the pure
// shuffle/FMA sweep. Same math/addresses as rounds 6-14.
// ---------------------------------------------------------------------------
template<bool RESID>
__global__ __launch_bounds__(256) void k_dwconv(
    const unsigned short* __restrict__ in, const float* __restrict__ filt,
    const float* __restrict__ sc, const float* __restrict__ shv,
    const unsigned short* __restrict__ resid, void* __restrict__ outv)
{
    const int bid = blockIdx.x;
    const int b = bid >> 6, c4 = (bid >> 2) & 15, strip = bid & 3;
    const int H0 = strip << 4;
    const int c = c4 * 4 + (threadIdx.x >> 6);
    const int lane = threadIdx.x & 63;
    const size_t pbase = ((size_t)b * CD + c) * PLANE;
    const unsigned short* plane = in + pbase;
    const float* wp = filt + c * 49;
    float K[49];
#pragma unroll
    for (int q = 0; q < 49; ++q) K[q] = wp[q];
    const float scl = RESID ? 1.f : sc[c];
    const float shf = shv[c];
    const unsigned short* rplane = RESID ? (resid + pbase) : nullptr;
    float* oplane_f = RESID ? ((float*)outv + pbase) : nullptr;
    unsigned short* oplane_h = RESID ? nullptr : ((unsigned short*)outv + pbase);

    // phase 1: all 22 rows -> registers (independent loads, deep MLP)
    float rows[22];
#pragma unroll
    for (int rr = 0; rr < 22; ++rr) {
        const int ra = H0 + rr - 3;
        rows[rr] = (ra >= 0 && ra < 64) ? bf2f(plane[ra * 64 + lane]) : 0.f;
    }

    // phase 2: shuffle + FMA sweep
    float acc[7] = {0.f, 0.f, 0.f, 0.f, 0.f, 0.f, 0.f};
#pragma unroll
    for (int rr = 0; rr < 22; ++rr) {
        const float rowv = rows[rr];
        float sh[7];
        sh[3] = rowv;
#pragma unroll
        for (int d = 1; d <= 3; ++d) {
            float tp = __shfl(rowv, lane + d);
            sh[3 + d] = (lane + d < 64) ? tp : 0.f;
            float tm = __shfl(rowv, lane - d);
            sh[3 - d] = (lane - d >= 0) ? tm : 0.f;
        }
#pragma unroll
        for (int dy = 0; dy < 7; ++dy) {
            const int o = rr - dy;
            if (o >= 0 && o < 16) {
                const int slot = o % 7;
#pragma unroll
                for (int dx = 0; dx < 7; ++dx)
                    acc[slot] = fmaf(sh[dx], K[dy * 7 + dx], acc[slot]);
            }
        }
        const int done = rr - 6;
        if (done >= 0 && done < 16) {
            const int slot = done % 7;
            const int h = H0 + done;
            if (RESID) {
                oplane_f[h * 64 + lane] =
                    acc[slot] + shf + bf2f(rplane[h * 64 + lane]);
            } else {
                oplane_h[h * 64 + lane] =
                    (unsigned short)f2bf(acc[slot] * scl + shf);
            }
            acc[slot] = 0.f;
        }
    }
}

// ---------------------------------------------------------------------------
// K3: fused KAN + f2 + gate + g-conv + BN via bf16 MFMA. (unchanged from
// round 14 — investigation closed at its 42us issue floor)
// ---------------------------------------------------------------------------
__global__ __launch_bounds__(256) void k_kan_fused(
    const unsigned short* __restrict__ xd, const short* __restrict__ W1f,
    const short* __restrict__ W2f, const short* __restrict__ WGf,
    const float* __restrict__ kb, const float* __restrict__ f2b,
    const float* __restrict__ gs, const float* __restrict__ gsh,
    unsigned short* __restrict__ z)
{
    __shared__ __align__(16) short As1[2 * 18 * 64 * 8];  // 36 KB
    __shared__ __align__(16) short As2[2 * 2 * 64 * 8];   //  4 KB
    __shared__ unsigned yPad[64 * 17];                    // 4.25 KB
    const int tid = threadIdx.x;
    const int tg0 = blockIdx.x * 32;
    const int bb = tg0 >> 12, pix0 = tg0 & 4095;
    const unsigned short* xb = xd + (size_t)bb * CD * PLANE + pix0;
    unsigned short* zb = z + (size_t)bb * CD * PLANE + pix0;
    const int tkn = tid & 31;
    const int w5 = tid >> 5;
    const int mt = tkn >> 4, m = tkn & 15;

    float vf[8], sf[8];
#pragma unroll
    for (int p = 0; p < 8; ++p) {
        const int c = w5 * 8 + p;
        const float v = bf2f(xb[(size_t)c * PLANE + tkn]);
        vf[p] = v;
        sf[p] = v * __builtin_amdgcn_rcpf(1.0f + __expf(-v));
        const u32x4 D = basisD(v);
        const int s = w5 * 2 + (p >> 2);
        const int phys = (((p & 3) << 4) | m) ^ (s & 7);
        *(u32x4*)&As1[((mt * 18 + s) * 64 + phys) * 8] = D;
    }
    {
        short8v vpk, spk;
#pragma unroll
        for (int q = 0; q < 4; ++q) {
            ((unsigned*)&vpk)[q] = cvtpk(vf[2 * q], vf[2 * q + 1]);
            ((unsigned*)&spk)[q] = cvtpk(sf[2 * q], sf[2 * q + 1]);
        }
        const int slot = ((w5 & 3) << 4) | m;
        const int s2 = 16 + (w5 >> 2);
        *(short8v*)&As1[((mt * 18 + s2) * 64 + (slot ^ (s2 & 7))) * 8] = spk;
        const int s3 = w5 >> 2;
        *(short8v*)&As2[((mt * 2 + s3) * 64 + (slot ^ (s3 & 7))) * 8] = vpk;
    }
    __syncthreads();   // B1

    const int cw = tid >> 6, l = tid & 63;
    const int hi = l >> 4;
    const int j = (cw << 4) + (l & 15);
    const int mq = l & 15;
    const int rb = hi << 2;
    const float kbj = kb[j], f2bj = f2b[j];
    const float sj = gs[j], hj = gsh[j];

    f32x4 accA0 = {0.f,0.f,0.f,0.f}, accA1 = {0.f,0.f,0.f,0.f};
    f32x4 accB0 = {0.f,0.f,0.f,0.f}, accB1 = {0.f,0.f,0.f,0.f};
#pragma unroll
    for (int s = 0; s < 18; ++s) {
        const short8v bfr = *(const short8v*)&W1f[((s * 4 + cw) * 64 + l) * 8];
        const short8v a0 = *(const short8v*)&As1[((0 * 18 + s) * 64 + (l ^ (s & 7))) * 8];
        const short8v a1 = *(const short8v*)&As1[((1 * 18 + s) * 64 + (l ^ (s & 7))) * 8];
        accA0 = __builtin_amdgcn_mfma_f32_16x16x32_bf16(a0, bfr, accA0, 0, 0, 0);
        accA1 = __builtin_amdgcn_mfma_f32_16x16x32_bf16(a1, bfr, accA1, 0, 0, 0);
    }
#pragma unroll
    for (int s = 0; s < 2; ++s) {
        const short8v bfr = *(const short8v*)&W2f[((s * 4 + cw) * 64 + l) * 8];
        const short8v a0 = *(const short8v*)&As2[((0 * 2 + s) * 64 + (l ^ s)) * 8];
        const short8v a1 = *(const short8v*)&As2[((1 * 2 + s) * 64 + (l ^ s)) * 8];
        accB0 = __builtin_amdgcn_mfma_f32_16x16x32_bf16(a0, bfr, accB0, 0, 0, 0);
        accB1 = __builtin_amdgcn_mfma_f32_16x16x32_bf16(a1, bfr, accB1, 0, 0, 0);
    }

#pragma unroll
    for (int r = 0; r < 4; ++r) {
        const float ya = (accA0[r] + kbj) * (accB0[r] + f2bj);
        const float yb = (accA1[r] + kbj) * (accB1[r] + f2bj);
        yPad[j * 17 + rb + r] = cvtpk(ya, yb);
    }
    __syncthreads();   // B2

    f32x4 acc30 = {0.f,0.f,0.f,0.f}, acc31 = {0.f,0.f,0.f,0.f};
#pragma unroll
    for (int s3 = 0; s3 < 2; ++s3) {
        const short8v bfr = *(const short8v*)&WGf[((s3 * 4 + cw) * 64 + l) * 8];
        short8v f0, f1;
        gather_frags(yPad, s3, hi, mq, f0, f1);
        acc30 = __builtin_amdgcn_mfma_f32_16x16x32_bf16(f0, bfr, acc30, 0, 0, 0);
        acc31 = __builtin_amdgcn_mfma_f32_16x16x32_bf16(f1, bfr, acc31, 0, 0, 0);
    }

    uint2 p0, p1;
    p0.x = cvtpk(acc30[0] * sj + hj, acc30[1] * sj + hj);
    p0.y = cvtpk(acc30[2] * sj + hj, acc30[3] * sj + hj);
    p1.x = cvtpk(acc31[0] * sj + hj, acc31[1] * sj + hj);
    p1.y = cvtpk(acc31[2] * sj + hj, acc31[3] * sj + hj);
    *(uint2*)&zb[(size_t)j * PLANE + rb] = p0;
    *(uint2*)&zb[(size_t)j * PLANE + 16 + rb] = p1;
}

// ---------------------------------------------------------------------------
extern "C" void kernel_launch(void* const* d_in, const int* in_sizes, int n_in,
                              void* d_out, int out_size, void* d_ws, size_t ws_size,
                              hipStream_t stream)
{
    (void)in_sizes; (void)n_in; (void)out_size; (void)ws_size;
    const float* x        = (const float*)d_in[0];
    const float* reduce_w = (const float*)d_in[1];
    const float* reduce_b = (const float*)d_in[2];
    const float* dw_w     = (const float*)d_in[3];
    const float* dw_b     = (const float*)d_in[4];
    const float* dw_g     = (const float*)d_in[5];
    const float* dw_beta  = (const float*)d_in[6];
    const float* dw_m     = (const float*)d_in[7];
    const float* dw_v     = (const float*)d_in[8];
    const float* f2_w     = (const float*)d_in[9];
    const float* f2_b     = (const float*)d_in[10];
    const float* coef     = (const float*)d_in[11];
    const float* sbase    = (const float*)d_in[12];
    const float* ssp      = (const float*)d_in[13];
    const float* kbias    = (const float*)d_in[14];
    const float* g_w      = (const float*)d_in[15];
    const float* g_b      = (const float*)d_in[16];
    const float* g_g      = (const float*)d_in[17];
    const float* g_beta   = (const float*)d_in[18];
    const float* g_m      = (const float*)d_in[19];
    const float* g_v      = (const float*)d_in[20];
    const float* dw2_w    = (const float*)d_in[21];
    const float* dw2_b    = (const float*)d_in[22];
    float* out = (float*)d_out;

    const size_t NEL = (size_t)BSZ * CD * PLANE;
    short* W1f = (short*)d_ws;
    short* W2f = W1f + 36864;
    short* WRf = W2f + 8192;
    short* WGf = WRf + 8192;
    float* cbuf = (float*)((char*)d_ws + 115200);
    unsigned short* inp = (unsigned short*)((char*)d_ws + 131072);  // bf16
    unsigned short* xdb = inp + NEL;                                // bf16
    unsigned short* z   = xdb + NEL;                                // bf16

    k_prep<<<225, 256, 0, stream>>>(coef, ssp, sbase, f2_w, reduce_w, g_w,
                                    dw_g, dw_beta, dw_m, dw_v, dw_b,
                                    g_g, g_beta, g_m, g_v, g_b,
                                    W1f, W2f, WRf, WGf, cbuf);
    k_reduce_mfma<<<BSZ * 32, 256, 0, stream>>>(x, WRf, reduce_b, inp);
    k_dwconv<false><<<BSZ * 16 * 4, 256, 0, stream>>>(inp, dw_w, cbuf, cbuf + 64, nullptr, xdb);
    k_kan_fused<<<NPIX / 32, 256, 0, stream>>>(xdb, W1f, W2f, WGf, kbias, f2_b,
                                               cbuf + 128, cbuf + 192, z);
    k_dwconv<true><<<BSZ * 16 * 4, 256, 0, stream>>>(z, dw2_w, nullptr, dw2_b, inp, out);
}

// Round 16
// 96.491 us; speedup vs baseline: 1.0765x; 1.0068x over previous
//
#include <hip/hip_runtime.h>
#include <hip/hip_bf16.h>

#define BSZ 32
#define CIN 128
#define CD 64
#define HH 64
#define WW 64
#define PLANE (HH * WW)
#define NPIX (BSZ * HH * WW)
#define NB 8
#define BN_EPS 1e-5f

typedef __attribute__((ext_vector_type(8))) short short8v;
typedef __attribute__((ext_vector_type(4))) float f32x4;
typedef __attribute__((ext_vector_type(4))) unsigned int u32x4;

static __device__ __forceinline__ short f2bf(float f) {
    __hip_bfloat16 h = __float2bfloat16(f);
    return __builtin_bit_cast(short, h);
}
static __device__ __forceinline__ float bf2f(unsigned short u) {
    return __builtin_bit_cast(float, (unsigned)u << 16);
}
// ROUND 16: packed bf16 convert WITHOUT inline asm (catalog m240: hand-asm
// cvt_pk is -37% vs scalar casts — asm blocks are scheduler-opaque; the
// compiler emits v_cvt_pk_bf16_f32 itself where profitable and can fuse /
// dual-issue around plain casts). RNE either way => bit-identical output.
static __device__ __forceinline__ unsigned int cvtpk(float lo, float hi) {
    const unsigned a = (unsigned short)__builtin_bit_cast(short, __float2bfloat16(lo));
    const unsigned b = (unsigned short)__builtin_bit_cast(short, __float2bfloat16(hi));
    return a | (b << 16);
}
// closed-form uniform cubic B-spline 8-slot window, funnel-shift placement
// (verified rounds 6-15).
static __device__ __forceinline__ u32x4 basisD(float v) {
    const float tt = (v + 2.2f) * 2.5f;
    const float fi = floorf(tt);
    const int i0 = (int)fi;
    const float u = tt - fi;
    const bool inr = (tt >= 0.0f) && (tt < 11.0f);
    const float u2 = u * u, u3 = u2 * u;
    const float t1 = 1.f - u;
    const float w0 = (1.f / 6.f) * t1 * t1 * t1;
    const float w3 = (1.f / 6.f) * u3;
    const float w1 = fmaf(0.5f, u3, 2.f / 3.f) - u2;
    const float w2 = 1.f - w0 - w1 - w3;
    unsigned W01 = cvtpk(w0, w1);
    unsigned W23 = cvtpk(w2, w3);
    if (!inr) { W01 = 0u; W23 = 0u; }
    const unsigned long long P =
        ((unsigned long long)W23 << 32) | (unsigned long long)W01;
    const int t = (i0 - 3) << 4;
    const unsigned long long S1 = P << (t & 63);
    const unsigned long long S2 = P >> ((64 - t) & 63);
    const bool c1 = (unsigned)t < 64u;
    const bool c2 = t < 0;
    const bool c3 = t >= 64;
    const bool c5 = t > 0;
    const unsigned long long lo = c1 ? S1 : (c2 ? S2 : 0ULL);
    const unsigned long long hi = c3 ? S1 : ((c1 && c5) ? S2 : 0ULL);
    u32x4 D;
    D.x = (unsigned)lo;
    D.y = (unsigned)(lo >> 32);
    D.z = (unsigned)hi;
    D.w = (unsigned)(hi >> 32);
    return D;
}
// rebuild tile0/tile1 bf16 A-frags from a [ch][17] (tile0,tile1)-pair pad
static __device__ __forceinline__ void gather_frags(
    const unsigned* __restrict__ pad, int s3, int hi, int m,
    short8v& f0, short8v& f1)
{
    unsigned q[8];
#pragma unroll
    for (int e = 0; e < 8; ++e) q[e] = pad[(s3 * 32 + 8 * hi + e) * 17 + m];
#pragma unroll
    for (int qi = 0; qi < 4; ++qi) {
        ((unsigned*)&f0)[qi] = (q[2 * qi] & 0xffffu) | (q[2 * qi + 1] << 16);
        ((unsigned*)&f1)[qi] = (q[2 * qi] >> 16) | (q[2 * qi + 1] & 0xffff0000u);
    }
}

// ---------------------------------------------------------------------------
// K0: prepack weights into MFMA B-fragment order (bf16) + fold BN.
// Fragment layout (verified round 2): element ((s*4+c)*64+l)*8+e holds
// W[k = s*32 + (l>>4)*8 + e][j = c*16 + (l&15)].
// ---------------------------------------------------------------------------
__global__ __launch_bounds__(256) void k_prep(
    const float* __restrict__ coef, const float* __restrict__ ssp,
    const float* __restrict__ sb, const float* __restrict__ f2w,
    const float* __restrict__ reduce_w, const float* __restrict__ g_w,
    const float* __restrict__ dw_g, const float* __restrict__ dw_beta,
    const float* __restrict__ dw_m, const float* __restrict__ dw_v,
    const float* __restrict__ dw_b, const float* __restrict__ g_g,
    const float* __restrict__ g_beta, const float* __restrict__ g_m,
    const float* __restrict__ g_v, const float* __restrict__ g_b,
    short* __restrict__ W1f, short* __restrict__ W2f,
    short* __restrict__ WRf, short* __restrict__ WGf,
    float* __restrict__ cbuf)
{
    const int idx = blockIdx.x * 256 + threadIdx.x;
    if (idx < 36864) {
        const int e = idx & 7, l = (idx >> 3) & 63, c = (idx >> 9) & 3, s = idx >> 11;
        const int k = s * 32 + ((l >> 4) << 3) + e;
        const int j = (c << 4) + (l & 15);
        float v;
        if (k < 512) {
            const int i = k >> 3, t = k & 7;
            v = coef[(i * 64 + j) * 8 + t] * ssp[i * 64 + j];
        } else {
            v = sb[(k - 512) * 64 + j];
        }
        W1f[idx] = f2bf(v);
    } else if (idx < 45056) {
        const int f = idx - 36864;
        const int e = f & 7, l = (f >> 3) & 63, c = (f >> 9) & 3, s = f >> 11;
        const int k = s * 32 + ((l >> 4) << 3) + e;
        const int j = (c << 4) + (l & 15);
        W2f[f] = f2bf(f2w[j * 64 + k]);
    } else if (idx < 53248) {
        const int f = idx - 45056;
        const int e = f & 7, l = (f >> 3) & 63, c = (f >> 9) & 3, s = f >> 11;
        const int k = s * 32 + ((l >> 4) << 3) + e;
        const int j = (c << 4) + (l & 15);
        WRf[f] = f2bf(reduce_w[j * CIN + k]);
    } else if (idx < 57344) {
        const int f = idx - 53248;
        const int e = f & 7, l = (f >> 3) & 63, c = (f >> 9) & 3, s = f >> 11;
        const int k = s * 32 + ((l >> 4) << 3) + e;
        const int j = (c << 4) + (l & 15);
        WGf[f] = f2bf(g_w[j * 64 + k]);
    } else if (idx < 57600) {
        const int q = (idx - 57344) >> 6, c = idx & 63;
        if (q == 0) cbuf[c] = dw_g[c] * rsqrtf(dw_v[c] + BN_EPS);
        else if (q == 1) {
            float sc = dw_g[c] * rsqrtf(dw_v[c] + BN_EPS);
            cbuf[64 + c] = (dw_b[c] - dw_m[c]) * sc + dw_beta[c];
        } else if (q == 2) cbuf[128 + c] = g_g[c] * rsqrtf(g_v[c] + BN_EPS);
        else {
            float sc = g_g[c] * rsqrtf(g_v[c] + BN_EPS);
            cbuf[192 + c] = (g_b[c] - g_m[c]) * sc + g_beta[c];
        }
    }
}

// ---------------------------------------------------------------------------
// K1: 1x1 conv 128->64 via MFMA, bf16 out. (round-15 structure; cvtpk now
// intrinsic-based)
// ---------------------------------------------------------------------------
__global__ __launch_bounds__(256) void k_reduce_mfma(
    const float* __restrict__ x, const short* __restrict__ WRf,
    const float* __restrict__ bias, unsigned short* __restrict__ out)
{
    __shared__ __align__(16) char smem[34048];
    short* As = (short*)smem;
    float* Osh = (float*)smem;
    const int bid = blockIdx.x;
    const int b = bid >> 5, h0 = (bid & 31) * 2;
    const int tid = threadIdx.x;
    const float* xb = x + (size_t)b * CIN * PLANE + h0 * WW;
#pragma unroll 1
    for (int p = 0; p < 32; ++p) {
        const int idx = tid + (p << 8);
        const int cpr = idx >> 7, rt = idx & 127;
        const int ca = cpr * 2;
        const float v0 = xb[(size_t)ca * PLANE + rt];
        const float v1 = xb[(size_t)(ca + 1) * PLANE + rt];
        const unsigned pk = cvtpk(v0, v1);
        const int s = ca >> 5, g = (ca >> 3) & 3, e = ca & 7;
        const int mt = rt >> 4, m = rt & 15;
        *(unsigned*)&As[((mt * 4 + s) * 64 + (((g << 4) | m) ^ (s & 7))) * 8 + e] = pk;
    }
    __syncthreads();
    const int cw = tid >> 6, l = tid & 63;
    f32x4 acc[8];
#pragma unroll
    for (int i = 0; i < 8; ++i) acc[i] = (f32x4){0.f, 0.f, 0.f, 0.f};
#pragma unroll 1
    for (int s = 0; s < 4; ++s) {
        const short8v bfr = *(const short8v*)&WRf[((s * 4 + cw) * 64 + l) * 8];
        const int lx = l ^ (s & 7);
#pragma unroll
        for (int mt = 0; mt < 8; ++mt) {
            const short8v a = *(const short8v*)&As[((mt * 4 + s) * 64 + lx) * 8];
            acc[mt] = __builtin_amdgcn_mfma_f32_16x16x32_bf16(a, bfr, acc[mt], 0, 0, 0);
        }
    }
    __syncthreads();
    const int j = (cw << 4) + (l & 15);
    const float bj = bias[j];
    const int rb = (l >> 4) << 2;
#pragma unroll
    for (int mt = 0; mt < 8; ++mt)
#pragma unroll
        for (int r = 0; r < 4; ++r)
            Osh[j * 133 + mt * 16 + rb + r] = acc[mt][r] + bj;
    __syncthreads();
    unsigned short* ob = out + (size_t)b * CD * PLANE + h0 * WW;
#pragma unroll 1
    for (int p = 0; p < 16; ++p) {
        const int idx = tid + (p << 8);
        const int jj = idx >> 6, rt2 = (idx & 63) * 2;
        const unsigned pk = cvtpk(Osh[jj * 133 + rt2], Osh[jj * 133 + rt2 + 1]);
        *(unsigned*)&ob[(size_t)jj * PLANE + rt2] = pk;
    }
}

// ---------------------------------------------------------------------------
// K2/K5: 7x7 depthwise conv, register-streaming, quarter-plane strips,
// two-phase row preload. (round-15 structure)
// ---------------------------------------------------------------------------
template<bool RESID>
__global__ __launch_bounds__(256) void k_dwconv(
    const unsigned short* __restrict__ in, const float* __restrict__ filt,
    const float* __restrict__ sc, const float* __restrict__ shv,
    const unsigned short* __restrict__ resid, void* __restrict__ outv)
{
    const int bid = blockIdx.x;
    const int b = bid >> 6, c4 = (bid >> 2) & 15, strip = bid & 3;
    const int H0 = strip << 4;
    const int c = c4 * 4 + (threadIdx.x >> 6);
    const int lane = threadIdx.x & 63;
    const size_t pbase = ((size_t)b * CD + c) * PLANE;
    const unsigned short* plane = in + pbase;
    const float* wp = filt + c * 49;
    float K[49];
#pragma unroll
    for (int q = 0; q < 49; ++q) K[q] = wp[q];
    const float scl = RESID ? 1.f : sc[c];
    const float shf = shv[c];
    const unsigned short* rplane = RESID ? (resid + pbase) : nullptr;
    float* oplane_f = RESID ? ((float*)outv + pbase) : nullptr;
    unsigned short* oplane_h = RESID ? nullptr : ((unsigned short*)outv + pbase);

    // phase 1: all 22 rows -> registers (independent loads, deep MLP)
    float rows[22];
#pragma unroll
    for (int rr = 0; rr < 22; ++rr) {
        const int ra = H0 + rr - 3;
        rows[rr] = (ra >= 0 && ra < 64) ? bf2f(plane[ra * 64 + lane]) : 0.f;
    }

    // phase 2: shuffle + FMA sweep
    float acc[7] = {0.f, 0.f, 0.f, 0.f, 0.f, 0.f, 0.f};
#pragma unroll
    for (int rr = 0; rr < 22; ++rr) {
        const float rowv = rows[rr];
        float sh[7];
        sh[3] = rowv;
#pragma unroll
        for (int d = 1; d <= 3; ++d) {
            float tp = __shfl(rowv, lane + d);
            sh[3 + d] = (lane + d < 64) ? tp : 0.f;
            float tm = __shfl(rowv, lane - d);
            sh[3 - d] = (lane - d >= 0) ? tm : 0.f;
        }
#pragma unroll
        for (int dy = 0; dy < 7; ++dy) {
            const int o = rr - dy;
            if (o >= 0 && o < 16) {
                const int slot = o % 7;
#pragma unroll
                for (int dx = 0; dx < 7; ++dx)
                    acc[slot] = fmaf(sh[dx], K[dy * 7 + dx], acc[slot]);
            }
        }
        const int done = rr - 6;
        if (done >= 0 && done < 16) {
            const int slot = done % 7;
            const int h = H0 + done;
            if (RESID) {
                oplane_f[h * 64 + lane] =
                    acc[slot] + shf + bf2f(rplane[h * 64 + lane]);
            } else {
                oplane_h[h * 64 + lane] =
                    (unsigned short)f2bf(acc[slot] * scl + shf);
            }
            acc[slot] = 0.f;
        }
    }
}

// ---------------------------------------------------------------------------
// K3: fused KAN + f2 + gate + g-conv + BN via bf16 MFMA. (round-15
// structure; cvtpk now intrinsic-based — the single variable this round)
// ---------------------------------------------------------------------------
__global__ __launch_bounds__(256) void k_kan_fused(
    const unsigned short* __restrict__ xd, const short* __restrict__ W1f,
    const short* __restrict__ W2f, const short* __restrict__ WGf,
    const float* __restrict__ kb, const float* __restrict__ f2b,
    const float* __restrict__ gs, const float* __restrict__ gsh,
    unsigned short* __restrict__ z)
{
    __shared__ __align__(16) short As1[2 * 18 * 64 * 8];  // 36 KB
    __shared__ __align__(16) short As2[2 * 2 * 64 * 8];   //  4 KB
    __shared__ unsigned yPad[64 * 17];                    // 4.25 KB
    const int tid = threadIdx.x;
    const int tg0 = blockIdx.x * 32;
    const int bb = tg0 >> 12, pix0 = tg0 & 4095;
    const unsigned short* xb = xd + (size_t)bb * CD * PLANE + pix0;
    unsigned short* zb = z + (size_t)bb * CD * PLANE + pix0;
    const int tkn = tid & 31;
    const int w5 = tid >> 5;
    const int mt = tkn >> 4, m = tkn & 15;

    float vf[8], sf[8];
#pragma unroll
    for (int p = 0; p < 8; ++p) {
        const int c = w5 * 8 + p;
        const float v = bf2f(xb[(size_t)c * PLANE + tkn]);
        vf[p] = v;
        sf[p] = v * __builtin_amdgcn_rcpf(1.0f + __expf(-v));
        const u32x4 D = basisD(v);
        const int s = w5 * 2 + (p >> 2);
        const int phys = (((p & 3) << 4) | m) ^ (s & 7);
        *(u32x4*)&As1[((mt * 18 + s) * 64 + phys) * 8] = D;
    }
    {
        short8v vpk, spk;
#pragma unroll
        for (int q = 0; q < 4; ++q) {
            ((unsigned*)&vpk)[q] = cvtpk(vf[2 * q], vf[2 * q + 1]);
            ((unsigned*)&spk)[q] = cvtpk(sf[2 * q], sf[2 * q + 1]);
        }
        const int slot = ((w5 & 3) << 4) | m;
        const int s2 = 16 + (w5 >> 2);
        *(short8v*)&As1[((mt * 18 + s2) * 64 + (slot ^ (s2 & 7))) * 8] = spk;
        const int s3 = w5 >> 2;
        *(short8v*)&As2[((mt * 2 + s3) * 64 + (slot ^ (s3 & 7))) * 8] = vpk;
    }
    __syncthreads();   // B1

    const int cw = tid >> 6, l = tid & 63;
    const int hi = l >> 4;
    const int j = (cw << 4) + (l & 15);
    const int mq = l & 15;
    const int rb = hi << 2;
    const float kbj = kb[j], f2bj = f2b[j];
    const float sj = gs[j], hj = gsh[j];

    f32x4 accA0 = {0.f,0.f,0.f,0.f}, accA1 = {0.f,0.f,0.f,0.f};
    f32x4 accB0 = {0.f,0.f,0.f,0.f}, accB1 = {0.f,0.f,0.f,0.f};
#pragma unroll
    for (int s = 0; s < 18; ++s) {
        const short8v bfr = *(const short8v*)&W1f[((s * 4 + cw) * 64 + l) * 8];
        const short8v a0 = *(const short8v*)&As1[((0 * 18 + s) * 64 + (l ^ (s & 7))) * 8];
        const short8v a1 = *(const short8v*)&As1[((1 * 18 + s) * 64 + (l ^ (s & 7))) * 8];
        accA0 = __builtin_amdgcn_mfma_f32_16x16x32_bf16(a0, bfr, accA0, 0, 0, 0);
        accA1 = __builtin_amdgcn_mfma_f32_16x16x32_bf16(a1, bfr, accA1, 0, 0, 0);
    }
#pragma unroll
    for (int s = 0; s < 2; ++s) {
        const short8v bfr = *(const short8v*)&W2f[((s * 4 + cw) * 64 + l) * 8];
        const short8v a0 = *(const short8v*)&As2[((0 * 2 + s) * 64 + (l ^ s)) * 8];
        const short8v a1 = *(const short8v*)&As2[((1 * 2 + s) * 64 + (l ^ s)) * 8];
        accB0 = __builtin_amdgcn_mfma_f32_16x16x32_bf16(a0, bfr, accB0, 0, 0, 0);
        accB1 = __builtin_amdgcn_mfma_f32_16x16x32_bf16(a1, bfr, accB1, 0, 0, 0);
    }

#pragma unroll
    for (int r = 0; r < 4; ++r) {
        const float ya = (accA0[r] + kbj) * (accB0[r] + f2bj);
        const float yb = (accA1[r] + kbj) * (accB1[r] + f2bj);
        yPad[j * 17 + rb + r] = cvtpk(ya, yb);
    }
    __syncthreads();   // B2

    f32x4 acc30 = {0.f,0.f,0.f,0.f}, acc31 = {0.f,0.f,0.f,0.f};
#pragma unroll
    for (int s3 = 0; s3 < 2; ++s3) {
        const short8v bfr = *(const short8v*)&WGf[((s3 * 4 + cw) * 64 + l) * 8];
        short8v f0, f1;
        gather_frags(yPad, s3, hi, mq, f0, f1);
        acc30 = __builtin_amdgcn_mfma_f32_16x16x32_bf16(f0, bfr, acc30, 0, 0, 0);
        acc31 = __builtin_amdgcn_mfma_f32_16x16x32_bf16(f1, bfr, acc31, 0, 0, 0);
    }

    uint2 p0, p1;
    p0.x = cvtpk(acc30[0] * sj + hj, acc30[1] * sj + hj);
    p0.y = cvtpk(acc30[2] * sj + hj, acc30[3] * sj + hj);
    p1.x = cvtpk(acc31[0] * sj + hj, acc31[1] * sj + hj);
    p1.y = cvtpk(acc31[2] * sj + hj, acc31[3] * sj + hj);
    *(uint2*)&zb[(size_t)j * PLANE + rb] = p0;
    *(uint2*)&zb[(size_t)j * PLANE + 16 + rb] = p1;
}

// ---------------------------------------------------------------------------
extern "C" void kernel_launch(void* const* d_in, const int* in_sizes, int n_in,
                              void* d_out, int out_size, void* d_ws, size_t ws_size,
                              hipStream_t stream)
{
    (void)in_sizes; (void)n_in; (void)out_size; (void)ws_size;
    const float* x        = (const float*)d_in[0];
    const float* reduce_w = (const float*)d_in[1];
    const float* reduce_b = (const float*)d_in[2];
    const float* dw_w     = (const float*)d_in[3];
    const float* dw_b     = (const float*)d_in[4];
    const float* dw_g     = (const float*)d_in[5];
    const float* dw_beta  = (const float*)d_in[6];
    const float* dw_m     = (const float*)d_in[7];
    const float* dw_v     = (const float*)d_in[8];
    const float* f2_w     = (const float*)d_in[9];
    const float* f2_b     = (const float*)d_in[10];
    const float* coef     = (const float*)d_in[11];
    const float* sbase    = (const float*)d_in[12];
    const float* ssp      = (const float*)d_in[13];
    const float* kbias    = (const float*)d_in[14];
    const float* g_w      = (const float*)d_in[15];
    const float* g_b      = (const float*)d_in[16];
    const float* g_g      = (const float*)d_in[17];
    const float* g_beta   = (const float*)d_in[18];
    const float* g_m      = (const float*)d_in[19];
    const float* g_v      = (const float*)d_in[20];
    const float* dw2_w    = (const float*)d_in[21];
    const float* dw2_b    = (const float*)d_in[22];
    float* out = (float*)d_out;

    const size_t NEL = (size_t)BSZ * CD * PLANE;
    short* W1f = (short*)d_ws;
    short* W2f = W1f + 36864;
    short* WRf = W2f + 8192;
    short* WGf = WRf + 8192;
    float* cbuf = (float*)((char*)d_ws + 115200);
    unsigned short* inp = (unsigned short*)((char*)d_ws + 131072);  // bf16
    unsigned short* xdb = inp + NEL;                                // bf16
    unsigned short* z   = xdb + NEL;                                // bf16

    k_prep<<<225, 256, 0, stream>>>(coef, ssp, sbase, f2_w, reduce_w, g_w,
                                    dw_g, dw_beta, dw_m, dw_v, dw_b,
                                    g_g, g_beta, g_m, g_v, g_b,
                                    W1f, W2f, WRf, WGf, cbuf);
    k_reduce_mfma<<<BSZ * 32, 256, 0, stream>>>(x, WRf, reduce_b, inp);
    k_dwconv<false><<<BSZ * 16 * 4, 256, 0, stream>>>(inp, dw_w, cbuf, cbuf + 64, nullptr, xdb);
    k_kan_fused<<<NPIX / 32, 256, 0, stream>>>(xdb, W1f, W2f, WGf, kbias, f2_b,
                                               cbuf + 128, cbuf + 192, z);
    k_dwconv<true><<<BSZ * 16 * 4, 256, 0, stream>>>(z, dw2_w, nullptr, dw2_b, inp, out);
}

// Round 17
// 95.451 us; speedup vs baseline: 1.0883x; 1.0109x over previous
//
#include <hip/hip_runtime.h>
#include <hip/hip_bf16.h>

#define BSZ 32
#define CIN 128
#define CD 64
#define HH 64
#define WW 64
#define PLANE (HH * WW)
#define NPIX (BSZ * HH * WW)
#define NB 8
#define BN_EPS 1e-5f

typedef __attribute__((ext_vector_type(8))) short short8v;
typedef __attribute__((ext_vector_type(4))) float f32x4;
typedef __attribute__((ext_vector_type(4))) unsigned int u32x4;

static __device__ __forceinline__ short f2bf(float f) {
    __hip_bfloat16 h = __float2bfloat16(f);
    return __builtin_bit_cast(short, h);
}
static __device__ __forceinline__ float bf2f(unsigned short u) {
    return __builtin_bit_cast(float, (unsigned)u << 16);
}
// ROUND 17 split (measured r15 vs r16): kan is faster with the ASM form
// (42.1 vs 44.2us); reduce/prep are faster with the intrinsic form
// (~2.8us aggregate). Use each where it measured best.
static __device__ __forceinline__ unsigned int cvtpk_a(float lo, float hi) {
    unsigned int r;
    asm("v_cvt_pk_bf16_f32 %0, %1, %2" : "=v"(r) : "v"(lo), "v"(hi));
    return r;
}
static __device__ __forceinline__ unsigned int cvtpk_i(float lo, float hi) {
    const unsigned a = (unsigned short)__builtin_bit_cast(short, __float2bfloat16(lo));
    const unsigned b = (unsigned short)__builtin_bit_cast(short, __float2bfloat16(hi));
    return a | (b << 16);
}
// closed-form uniform cubic B-spline 8-slot window, funnel-shift placement
// (verified rounds 6-16). kan-only => asm cvtpk.
static __device__ __forceinline__ u32x4 basisD(float v) {
    const float tt = (v + 2.2f) * 2.5f;
    const float fi = floorf(tt);
    const int i0 = (int)fi;
    const float u = tt - fi;
    const bool inr = (tt >= 0.0f) && (tt < 11.0f);
    const float u2 = u * u, u3 = u2 * u;
    const float t1 = 1.f - u;
    const float w0 = (1.f / 6.f) * t1 * t1 * t1;
    const float w3 = (1.f / 6.f) * u3;
    const float w1 = fmaf(0.5f, u3, 2.f / 3.f) - u2;
    const float w2 = 1.f - w0 - w1 - w3;
    unsigned W01 = cvtpk_a(w0, w1);
    unsigned W23 = cvtpk_a(w2, w3);
    if (!inr) { W01 = 0u; W23 = 0u; }
    const unsigned long long P =
        ((unsigned long long)W23 << 32) | (unsigned long long)W01;
    const int t = (i0 - 3) << 4;
    const unsigned long long S1 = P << (t & 63);
    const unsigned long long S2 = P >> ((64 - t) & 63);
    const bool c1 = (unsigned)t < 64u;
    const bool c2 = t < 0;
    const bool c3 = t >= 64;
    const bool c5 = t > 0;
    const unsigned long long lo = c1 ? S1 : (c2 ? S2 : 0ULL);
    const unsigned long long hi = c3 ? S1 : ((c1 && c5) ? S2 : 0ULL);
    u32x4 D;
    D.x = (unsigned)lo;
    D.y = (unsigned)(lo >> 32);
    D.z = (unsigned)hi;
    D.w = (unsigned)(hi >> 32);
    return D;
}
// rebuild tile0/tile1 bf16 A-frags from a [ch][17] (tile0,tile1)-pair pad
static __device__ __forceinline__ void gather_frags(
    const unsigned* __restrict__ pad, int s3, int hi, int m,
    short8v& f0, short8v& f1)
{
    unsigned q[8];
#pragma unroll
    for (int e = 0; e < 8; ++e) q[e] = pad[(s3 * 32 + 8 * hi + e) * 17 + m];
#pragma unroll
    for (int qi = 0; qi < 4; ++qi) {
        ((unsigned*)&f0)[qi] = (q[2 * qi] & 0xffffu) | (q[2 * qi + 1] << 16);
        ((unsigned*)&f1)[qi] = (q[2 * qi] >> 16) | (q[2 * qi + 1] & 0xffff0000u);
    }
}

// ---------------------------------------------------------------------------
// K0: prepack weights into MFMA B-fragment order (bf16) + fold BN.
// Fragment layout (verified round 2): element ((s*4+c)*64+l)*8+e holds
// W[k = s*32 + (l>>4)*8 + e][j = c*16 + (l&15)].
// ---------------------------------------------------------------------------
__global__ __launch_bounds__(256) void k_prep(
    const float* __restrict__ coef, const float* __restrict__ ssp,
    const float* __restrict__ sb, const float* __restrict__ f2w,
    const float* __restrict__ reduce_w, const float* __restrict__ g_w,
    const float* __restrict__ dw_g, const float* __restrict__ dw_beta,
    const float* __restrict__ dw_m, const float* __restrict__ dw_v,
    const float* __restrict__ dw_b, const float* __restrict__ g_g,
    const float* __restrict__ g_beta, const float* __restrict__ g_m,
    const float* __restrict__ g_v, const float* __restrict__ g_b,
    short* __restrict__ W1f, short* __restrict__ W2f,
    short* __restrict__ WRf, short* __restrict__ WGf,
    float* __restrict__ cbuf)
{
    const int idx = blockIdx.x * 256 + threadIdx.x;
    if (idx < 36864) {
        const int e = idx & 7, l = (idx >> 3) & 63, c = (idx >> 9) & 3, s = idx >> 11;
        const int k = s * 32 + ((l >> 4) << 3) + e;
        const int j = (c << 4) + (l & 15);
        float v;
        if (k < 512) {
            const int i = k >> 3, t = k & 7;
            v = coef[(i * 64 + j) * 8 + t] * ssp[i * 64 + j];
        } else {
            v = sb[(k - 512) * 64 + j];
        }
        W1f[idx] = f2bf(v);
    } else if (idx < 45056) {
        const int f = idx - 36864;
        const int e = f & 7, l = (f >> 3) & 63, c = (f >> 9) & 3, s = f >> 11;
        const int k = s * 32 + ((l >> 4) << 3) + e;
        const int j = (c << 4) + (l & 15);
        W2f[f] = f2bf(f2w[j * 64 + k]);
    } else if (idx < 53248) {
        const int f = idx - 45056;
        const int e = f & 7, l = (f >> 3) & 63, c = (f >> 9) & 3, s = f >> 11;
        const int k = s * 32 + ((l >> 4) << 3) + e;
        const int j = (c << 4) + (l & 15);
        WRf[f] = f2bf(reduce_w[j * CIN + k]);
    } else if (idx < 57344) {
        const int f = idx - 53248;
        const int e = f & 7, l = (f >> 3) & 63, c = (f >> 9) & 3, s = f >> 11;
        const int k = s * 32 + ((l >> 4) << 3) + e;
        const int j = (c << 4) + (l & 15);
        WGf[f] = f2bf(g_w[j * 64 + k]);
    } else if (idx < 57600) {
        const int q = (idx - 57344) >> 6, c = idx & 63;
        if (q == 0) cbuf[c] = dw_g[c] * rsqrtf(dw_v[c] + BN_EPS);
        else if (q == 1) {
            float sc = dw_g[c] * rsqrtf(dw_v[c] + BN_EPS);
            cbuf[64 + c] = (dw_b[c] - dw_m[c]) * sc + dw_beta[c];
        } else if (q == 2) cbuf[128 + c] = g_g[c] * rsqrtf(g_v[c] + BN_EPS);
        else {
            float sc = g_g[c] * rsqrtf(g_v[c] + BN_EPS);
            cbuf[192 + c] = (g_b[c] - g_m[c]) * sc + g_beta[c];
        }
    }
}

// ---------------------------------------------------------------------------
// K1: 1x1 conv 128->64 via MFMA, bf16 out. (round-16 form: intrinsic cvtpk)
// ---------------------------------------------------------------------------
__global__ __launch_bounds__(256) void k_reduce_mfma(
    const float* __restrict__ x, const short* __restrict__ WRf,
    const float* __restrict__ bias, unsigned short* __restrict__ out)
{
    __shared__ __align__(16) char smem[34048];
    short* As = (short*)smem;
    float* Osh = (float*)smem;
    const int bid = blockIdx.x;
    const int b = bid >> 5, h0 = (bid & 31) * 2;
    const int tid = threadIdx.x;
    const float* xb = x + (size_t)b * CIN * PLANE + h0 * WW;
#pragma unroll 1
    for (int p = 0; p < 32; ++p) {
        const int idx = tid + (p << 8);
        const int cpr = idx >> 7, rt = idx & 127;
        const int ca = cpr * 2;
        const float v0 = xb[(size_t)ca * PLANE + rt];
        const float v1 = xb[(size_t)(ca + 1) * PLANE + rt];
        const unsigned pk = cvtpk_i(v0, v1);
        const int s = ca >> 5, g = (ca >> 3) & 3, e = ca & 7;
        const int mt = rt >> 4, m = rt & 15;
        *(unsigned*)&As[((mt * 4 + s) * 64 + (((g << 4) | m) ^ (s & 7))) * 8 + e] = pk;
    }
    __syncthreads();
    const int cw = tid >> 6, l = tid & 63;
    f32x4 acc[8];
#pragma unroll
    for (int i = 0; i < 8; ++i) acc[i] = (f32x4){0.f, 0.f, 0.f, 0.f};
#pragma unroll 1
    for (int s = 0; s < 4; ++s) {
        const short8v bfr = *(const short8v*)&WRf[((s * 4 + cw) * 64 + l) * 8];
        const int lx = l ^ (s & 7);
#pragma unroll
        for (int mt = 0; mt < 8; ++mt) {
            const short8v a = *(const short8v*)&As[((mt * 4 + s) * 64 + lx) * 8];
            acc[mt] = __builtin_amdgcn_mfma_f32_16x16x32_bf16(a, bfr, acc[mt], 0, 0, 0);
        }
    }
    __syncthreads();
    const int j = (cw << 4) + (l & 15);
    const float bj = bias[j];
    const int rb = (l >> 4) << 2;
#pragma unroll
    for (int mt = 0; mt < 8; ++mt)
#pragma unroll
        for (int r = 0; r < 4; ++r)
            Osh[j * 133 + mt * 16 + rb + r] = acc[mt][r] + bj;
    __syncthreads();
    unsigned short* ob = out + (size_t)b * CD * PLANE + h0 * WW;
#pragma unroll 1
    for (int p = 0; p < 16; ++p) {
        const int idx = tid + (p << 8);
        const int jj = idx >> 6, rt2 = (idx & 63) * 2;
        const unsigned pk = cvtpk_i(Osh[jj * 133 + rt2], Osh[jj * 133 + rt2 + 1]);
        *(unsigned*)&ob[(size_t)jj * PLANE + rt2] = pk;
    }
}

// ---------------------------------------------------------------------------
// K2/K5: 7x7 depthwise conv, register-streaming, quarter-plane strips,
// two-phase row preload. (round-15/16 structure)
// ---------------------------------------------------------------------------
template<bool RESID>
__global__ __launch_bounds__(256) void k_dwconv(
    const unsigned short* __restrict__ in, const float* __restrict__ filt,
    const float* __restrict__ sc, const float* __restrict__ shv,
    const unsigned short* __restrict__ resid, void* __restrict__ outv)
{
    const int bid = blockIdx.x;
    const int b = bid >> 6, c4 = (bid >> 2) & 15, strip = bid & 3;
    const int H0 = strip << 4;
    const int c = c4 * 4 + (threadIdx.x >> 6);
    const int lane = threadIdx.x & 63;
    const size_t pbase = ((size_t)b * CD + c) * PLANE;
    const unsigned short* plane = in + pbase;
    const float* wp = filt + c * 49;
    float K[49];
#pragma unroll
    for (int q = 0; q < 49; ++q) K[q] = wp[q];
    const float scl = RESID ? 1.f : sc[c];
    const float shf = shv[c];
    const unsigned short* rplane = RESID ? (resid + pbase) : nullptr;
    float* oplane_f = RESID ? ((float*)outv + pbase) : nullptr;
    unsigned short* oplane_h = RESID ? nullptr : ((unsigned short*)outv + pbase);

    // phase 1: all 22 rows -> registers (independent loads, deep MLP)
    float rows[22];
#pragma unroll
    for (int rr = 0; rr < 22; ++rr) {
        const int ra = H0 + rr - 3;
        rows[rr] = (ra >= 0 && ra < 64) ? bf2f(plane[ra * 64 + lane]) : 0.f;
    }

    // phase 2: shuffle + FMA sweep
    float acc[7] = {0.f, 0.f, 0.f, 0.f, 0.f, 0.f, 0.f};
#pragma unroll
    for (int rr = 0; rr < 22; ++rr) {
        const float rowv = rows[rr];
        float sh[7];
        sh[3] = rowv;
#pragma unroll
        for (int d = 1; d <= 3; ++d) {
            float tp = __shfl(rowv, lane + d);
            sh[3 + d] = (lane + d < 64) ? tp : 0.f;
            float tm = __shfl(rowv, lane - d);
            sh[3 - d] = (lane - d >= 0) ? tm : 0.f;
        }
#pragma unroll
        for (int dy = 0; dy < 7; ++dy) {
            const int o = rr - dy;
            if (o >= 0 && o < 16) {
                const int slot = o % 7;
#pragma unroll
                for (int dx = 0; dx < 7; ++dx)
                    acc[slot] = fmaf(sh[dx], K[dy * 7 + dx], acc[slot]);
            }
        }
        const int done = rr - 6;
        if (done >= 0 && done < 16) {
            const int slot = done % 7;
            const int h = H0 + done;
            if (RESID) {
                oplane_f[h * 64 + lane] =
                    acc[slot] + shf + bf2f(rplane[h * 64 + lane]);
            } else {
                oplane_h[h * 64 + lane] =
                    (unsigned short)f2bf(acc[slot] * scl + shf);
            }
            acc[slot] = 0.f;
        }
    }
}

// ---------------------------------------------------------------------------
// K3: fused KAN + f2 + gate + g-conv + BN via bf16 MFMA. (round-15 form:
// ASM cvtpk — measured 2.1us faster than intrinsic in this kernel)
// ---------------------------------------------------------------------------
__global__ __launch_bounds__(256) void k_kan_fused(
    const unsigned short* __restrict__ xd, const short* __restrict__ W1f,
    const short* __restrict__ W2f, const short* __restrict__ WGf,
    const float* __restrict__ kb, const float* __restrict__ f2b,
    const float* __restrict__ gs, const float* __restrict__ gsh,
    unsigned short* __restrict__ z)
{
    __shared__ __align__(16) short As1[2 * 18 * 64 * 8];  // 36 KB
    __shared__ __align__(16) short As2[2 * 2 * 64 * 8];   //  4 KB
    __shared__ unsigned yPad[64 * 17];                    // 4.25 KB
    const int tid = threadIdx.x;
    const int tg0 = blockIdx.x * 32;
    const int bb = tg0 >> 12, pix0 = tg0 & 4095;
    const unsigned short* xb = xd + (size_t)bb * CD * PLANE + pix0;
    unsigned short* zb = z + (size_t)bb * CD * PLANE + pix0;
    const int tkn = tid & 31;
    const int w5 = tid >> 5;
    const int mt = tkn >> 4, m = tkn & 15;

    float vf[8], sf[8];
#pragma unroll
    for (int p = 0; p < 8; ++p) {
        const int c = w5 * 8 + p;
        const float v = bf2f(xb[(size_t)c * PLANE + tkn]);
        vf[p] = v;
        sf[p] = v * __builtin_amdgcn_rcpf(1.0f + __expf(-v));
        const u32x4 D = basisD(v);
        const int s = w5 * 2 + (p >> 2);
        const int phys = (((p & 3) << 4) | m) ^ (s & 7);
        *(u32x4*)&As1[((mt * 18 + s) * 64 + phys) * 8] = D;
    }
    {
        short8v vpk, spk;
#pragma unroll
        for (int q = 0; q < 4; ++q) {
            ((unsigned*)&vpk)[q] = cvtpk_a(vf[2 * q], vf[2 * q + 1]);
            ((unsigned*)&spk)[q] = cvtpk_a(sf[2 * q], sf[2 * q + 1]);
        }
        const int slot = ((w5 & 3) << 4) | m;
        const int s2 = 16 + (w5 >> 2);
        *(short8v*)&As1[((mt * 18 + s2) * 64 + (slot ^ (s2 & 7))) * 8] = spk;
        const int s3 = w5 >> 2;
        *(short8v*)&As2[((mt * 2 + s3) * 64 + (slot ^ (s3 & 7))) * 8] = vpk;
    }
    __syncthreads();   // B1

    const int cw = tid >> 6, l = tid & 63;
    const int hi = l >> 4;
    const int j = (cw << 4) + (l & 15);
    const int mq = l & 15;
    const int rb = hi << 2;
    const float kbj = kb[j], f2bj = f2b[j];
    const float sj = gs[j], hj = gsh[j];

    f32x4 accA0 = {0.f,0.f,0.f,0.f}, accA1 = {0.f,0.f,0.f,0.f};
    f32x4 accB0 = {0.f,0.f,0.f,0.f}, accB1 = {0.f,0.f,0.f,0.f};
#pragma unroll
    for (int s = 0; s < 18; ++s) {
        const short8v bfr = *(const short8v*)&W1f[((s * 4 + cw) * 64 + l) * 8];
        const short8v a0 = *(const short8v*)&As1[((0 * 18 + s) * 64 + (l ^ (s & 7))) * 8];
        const short8v a1 = *(const short8v*)&As1[((1 * 18 + s) * 64 + (l ^ (s & 7))) * 8];
        accA0 = __builtin_amdgcn_mfma_f32_16x16x32_bf16(a0, bfr, accA0, 0, 0, 0);
        accA1 = __builtin_amdgcn_mfma_f32_16x16x32_bf16(a1, bfr, accA1, 0, 0, 0);
    }
#pragma unroll
    for (int s = 0; s < 2; ++s) {
        const short8v bfr = *(const short8v*)&W2f[((s * 4 + cw) * 64 + l) * 8];
        const short8v a0 = *(const short8v*)&As2[((0 * 2 + s) * 64 + (l ^ s)) * 8];
        const short8v a1 = *(const short8v*)&As2[((1 * 2 + s) * 64 + (l ^ s)) * 8];
        accB0 = __builtin_amdgcn_mfma_f32_16x16x32_bf16(a0, bfr, accB0, 0, 0, 0);
        accB1 = __builtin_amdgcn_mfma_f32_16x16x32_bf16(a1, bfr, accB1, 0, 0, 0);
    }

#pragma unroll
    for (int r = 0; r < 4; ++r) {
        const float ya = (accA0[r] + kbj) * (accB0[r] + f2bj);
        const float yb = (accA1[r] + kbj) * (accB1[r] + f2bj);
        yPad[j * 17 + rb + r] = cvtpk_a(ya, yb);
    }
    __syncthreads();   // B2

    f32x4 acc30 = {0.f,0.f,0.f,0.f}, acc31 = {0.f,0.f,0.f,0.f};
#pragma unroll
    for (int s3 = 0; s3 < 2; ++s3) {
        const short8v bfr = *(const short8v*)&WGf[((s3 * 4 + cw) * 64 + l) * 8];
        short8v f0, f1;
        gather_frags(yPad, s3, hi, mq, f0, f1);
        acc30 = __builtin_amdgcn_mfma_f32_16x16x32_bf16(f0, bfr, acc30, 0, 0, 0);
        acc31 = __builtin_amdgcn_mfma_f32_16x16x32_bf16(f1, bfr, acc31, 0, 0, 0);
    }

    uint2 p0, p1;
    p0.x = cvtpk_a(acc30[0] * sj + hj, acc30[1] * sj + hj);
    p0.y = cvtpk_a(acc30[2] * sj + hj, acc30[3] * sj + hj);
    p1.x = cvtpk_a(acc31[0] * sj + hj, acc31[1] * sj + hj);
    p1.y = cvtpk_a(acc31[2] * sj + hj, acc31[3] * sj + hj);
    *(uint2*)&zb[(size_t)j * PLANE + rb] = p0;
    *(uint2*)&zb[(size_t)j * PLANE + 16 + rb] = p1;
}

// ---------------------------------------------------------------------------
extern "C" void kernel_launch(void* const* d_in, const int* in_sizes, int n_in,
                              void* d_out, int out_size, void* d_ws, size_t ws_size,
                              hipStream_t stream)
{
    (void)in_sizes; (void)n_in; (void)out_size; (void)ws_size;
    const float* x        = (const float*)d_in[0];
    const float* reduce_w = (const float*)d_in[1];
    const float* reduce_b = (const float*)d_in[2];
    const float* dw_w     = (const float*)d_in[3];
    const float* dw_b     = (const float*)d_in[4];
    const float* dw_g     = (const float*)d_in[5];
    const float* dw_beta  = (const float*)d_in[6];
    const float* dw_m     = (const float*)d_in[7];
    const float* dw_v     = (const float*)d_in[8];
    const float* f2_w     = (const float*)d_in[9];
    const float* f2_b     = (const float*)d_in[10];
    const float* coef     = (const float*)d_in[11];
    const float* sbase    = (const float*)d_in[12];
    const float* ssp      = (const float*)d_in[13];
    const float* kbias    = (const float*)d_in[14];
    const float* g_w      = (const float*)d_in[15];
    const float* g_b      = (const float*)d_in[16];
    const float* g_g      = (const float*)d_in[17];
    const float* g_beta   = (const float*)d_in[18];
    const float* g_m      = (const float*)d_in[19];
    const float* g_v      = (const float*)d_in[20];
    const float* dw2_w    = (const float*)d_in[21];
    const float* dw2_b    = (const float*)d_in[22];
    float* out = (float*)d_out;

    const size_t NEL = (size_t)BSZ * CD * PLANE;
    short* W1f = (short*)d_ws;
    short* W2f = W1f + 36864;
    short* WRf = W2f + 8192;
    short* WGf = WRf + 8192;
    float* cbuf = (float*)((char*)d_ws + 115200);
    unsigned short* inp = (unsigned short*)((char*)d_ws + 131072);  // bf16
    unsigned short* xdb = inp + NEL;                                // bf16
    unsigned short* z   = xdb + NEL;                                // bf16

    k_prep<<<225, 256, 0, stream>>>(coef, ssp, sbase, f2_w, reduce_w, g_w,
                                    dw_g, dw_beta, dw_m, dw_v, dw_b,
                                    g_g, g_beta, g_m, g_v, g_b,
                                    W1f, W2f, WRf, WGf, cbuf);
    k_reduce_mfma<<<BSZ * 32, 256, 0, stream>>>(x, WRf, reduce_b, inp);
    k_dwconv<false><<<BSZ * 16 * 4, 256, 0, stream>>>(inp, dw_w, cbuf, cbuf + 64, nullptr, xdb);
    k_kan_fused<<<NPIX / 32, 256, 0, stream>>>(xdb, W1f, W2f, WGf, kbias, f2_b,
                                               cbuf + 128, cbuf + 192, z);
    k_dwconv<true><<<BSZ * 16 * 4, 256, 0, stream>>>(z, dw2_w, nullptr, dw2_b, inp, out);
}